// Round 6
// baseline (14.076 us; speedup 1.0000x reference)
//
#include <hip/hip_runtime.h>
#include <math.h>

#define BATCH 2048
#define IN_DIM 784
#define NQ 14
#define NF 105
#define NC 10
#define HALF_CHUNKS 98   // 196 float4 per row, split across 2 waves

// Analytic collapse of the quantum feature map:
//   angles  = tanh(x @ proj_w.T + proj_b) * pi
//   c_q     = cos(angle_q)
//   final bit k of circuit = XOR of initial bits {k, k-2, k-4, ...}
//   <Z_i>    = prod_{q in S_i} c_q;  <Z_i Z_j> = prod over S_i XOR S_j
//   out      = feats @ cls_w.T + cls_b
// zmask(q) = (0x1555 << (q&1)) & ((2u<<q)-1)
//
// R6: 2 waves per row (each does half the 784 columns), one barrier, half-1
// waves retire after the combine write. 4096 waves -> 4/SIMD occupancy in the
// dominant dot-product phase; per-wave serial path ~30% shorter.

__device__ __forceinline__ unsigned zmask(int q) {
    return (0x1555u << (q & 1)) & ((2u << q) - 1u);
}

template <int CTRL>
__device__ __forceinline__ float dppadd(float x) {
    return x + __int_as_float(__builtin_amdgcn_update_dpp(
        0, __float_as_int(x), CTRL, 0xF, 0xF, true));
}

__device__ __forceinline__ float wave_allreduce(float x, int xor32addr) {
    x = dppadd<0xB1>(x);   // + lane^1
    x = dppadd<0x4E>(x);   // + lane^2
    x = dppadd<0x141>(x);  // + lane^4 (row_half_mirror)
    x = dppadd<0x140>(x);  // + lane^8 (row_mirror)
    x = x + __int_as_float(__builtin_amdgcn_ds_swizzle(__float_as_int(x), 0x401F)); // + lane^16
#if __has_builtin(__builtin_amdgcn_permlane32_swap)
    {
        typedef unsigned u2v __attribute__((ext_vector_type(2)));
        u2v r = __builtin_amdgcn_permlane32_swap(
            (unsigned)__float_as_int(x), (unsigned)__float_as_int(x), false, false);
        x = __int_as_float((int)r[0]) + __int_as_float((int)r[1]);  // x[l&~32]+x[l|32]
    }
#else
    x = x + __int_as_float(__builtin_amdgcn_ds_bpermute(xor32addr, __float_as_int(x)));
#endif
    return x;
}

__global__ __launch_bounds__(256) void qfm_kernel(
    const float* __restrict__ x,
    const float* __restrict__ pw,
    const float* __restrict__ pb,
    const float* __restrict__ cw,
    const float* __restrict__ cb,
    float* __restrict__ out)
{
    const int t    = (int)threadIdx.x;
    const int lane = t & 63;
    const int wv   = t >> 6;        // 0..3
    const int rb   = wv >> 1;       // row within block (0,1)
    const int half = wv & 1;        // column half
    const int row  = (int)blockIdx.x * 2 + rb;
    const int xor32addr = ((lane ^ 32) << 2);

    __shared__ __align__(16) float part[2][2][16];   // [row][half][q padded]

    // ---- this wave's half of the x row: chunk lane, and chunk 64+lane if lane<34 ----
    const float4* xr4 = reinterpret_cast<const float4*>(x + (size_t)row * IN_DIM)
                        + half * HALF_CHUNKS;
    const float4 xv0 = xr4[lane];
    float4 xv1 = make_float4(0.f, 0.f, 0.f, 0.f);
    if (lane < HALF_CHUNKS - 64) xv1 = xr4[64 + lane];

    // ---- 14 partial dots over this half (independent chains) ----
    float acc[NQ];
#pragma unroll
    for (int q = 0; q < NQ; ++q) {
        const float4* wr4 = reinterpret_cast<const float4*>(pw + (size_t)q * IN_DIM)
                            + half * HALF_CHUNKS;
        const float4 w0 = wr4[lane];
        float a = xv0.x * w0.x + xv0.y * w0.y + xv0.z * w0.z + xv0.w * w0.w;
        if (lane < HALF_CHUNKS - 64) {
            const float4 w1 = wr4[64 + lane];
            a += xv1.x * w1.x + xv1.y * w1.y + xv1.z * w1.z + xv1.w * w1.w;
        }
        acc[q] = a;
    }

    // ---- wave allreduce per q (VALU DPP butterflies) ----
#pragma unroll
    for (int q = 0; q < NQ; ++q) acc[q] = wave_allreduce(acc[q], xor32addr);

    // ---- lane 0 writes the 14 partials (packed, static indices) ----
    if (lane == 0) {
        float4* p4 = reinterpret_cast<float4*>(&part[rb][half][0]);
        p4[0] = make_float4(acc[0], acc[1], acc[2],  acc[3]);
        p4[1] = make_float4(acc[4], acc[5], acc[6],  acc[7]);
        p4[2] = make_float4(acc[8], acc[9], acc[10], acc[11]);
        reinterpret_cast<float2*>(&part[rb][half][12])[0] = make_float2(acc[12], acc[13]);
    }
    __syncthreads();
    if (half) return;   // half-1 waves retire; SIMD slots free up

    // ---- combine halves (uniform-address LDS reads -> broadcast) ----
    const float4* a4 = reinterpret_cast<const float4*>(&part[rb][0][0]);
    const float4* b4 = reinterpret_cast<const float4*>(&part[rb][1][0]);
    const float4 s0 = a4[0], s1 = a4[1], s2 = a4[2];
    const float4 t0 = b4[0], t1 = b4[1], t2 = b4[2];
    const float2 s3 = reinterpret_cast<const float2*>(&part[rb][0][12])[0];
    const float2 t3 = reinterpret_cast<const float2*>(&part[rb][1][12])[0];
    float sum[NQ] = {
        s0.x + t0.x, s0.y + t0.y, s0.z + t0.z, s0.w + t0.w,
        s1.x + t1.x, s1.y + t1.y, s1.z + t1.z, s1.w + t1.w,
        s2.x + t2.x, s2.y + t2.y, s2.z + t2.z, s2.w + t2.w,
        s3.x + t3.x, s3.y + t3.y };

    // ---- fast cos(pi * tanh(a)) ----
    float c[NQ];
#pragma unroll
    for (int q = 0; q < NQ; ++q) {
        const float a = sum[q] + pb[q];
        const float e = __expf(2.0f * a);                 // e^{2a}
        const float r = __builtin_amdgcn_rcpf(e + 1.0f);  // 1/(e^{2a}+1)
        const float tt = fmaf(-2.0f, r, 1.0f);            // tanh(a)
        c[q] = __cosf(3.14159265358979323846f * tt);      // cos(pi*tanh)
    }

    // ---- features: lane handles f = lane and f = lane + 64 ----
    float acc_out[NC];
#pragma unroll
    for (int k = 0; k < NC; ++k) acc_out[k] = 0.f;

#pragma unroll
    for (int rep = 0; rep < 2; ++rep) {
        const int f = lane + rep * 64;
        if (f < NF) {
            unsigned m;
            if (f < NQ) {
                m = zmask(f);
            } else {
                const int g = f - NQ;                     // 0..90 triangular decode
                const float sq = __builtin_amdgcn_sqrtf(182.25f - 2.0f * (float)g);
                const int i = (int)(13.5f - sq + 1.0e-4f);
                const int j = i + 1 + g - (i * (27 - i)) / 2;
                m = zmask(i) ^ zmask(j);
            }
            float prod = 1.f;
#pragma unroll
            for (int q = 0; q < NQ; ++q) {
                const float mult = ((m >> q) & 1u) ? c[q] : 1.0f;
                prod *= mult;
            }
#pragma unroll
            for (int k = 0; k < NC; ++k)
                acc_out[k] += cw[k * NF + f] * prod;
        }
    }

    // ---- 10 output reductions; lanes 0..9 write coalesced ----
    float myout = 0.f;
#pragma unroll
    for (int k = 0; k < NC; ++k) {
        const float a = wave_allreduce(acc_out[k], xor32addr);
        if (lane == k) myout = a + cb[k];
    }
    if (lane < NC) out[(size_t)row * NC + lane] = myout;
}

extern "C" void kernel_launch(void* const* d_in, const int* in_sizes, int n_in,
                              void* d_out, int out_size, void* d_ws, size_t ws_size,
                              hipStream_t stream) {
    const float* x  = (const float*)d_in[0];
    const float* pw = (const float*)d_in[1];
    const float* pb = (const float*)d_in[2];
    const float* cw = (const float*)d_in[3];
    const float* cb = (const float*)d_in[4];
    float* out = (float*)d_out;

    qfm_kernel<<<dim3(BATCH / 2), dim3(256), 0, stream>>>(x, pw, pb, cw, cb, out);
}

// Round 7
// 12.950 us; speedup vs baseline: 1.0869x; 1.0869x over previous
//
#include <hip/hip_runtime.h>
#include <math.h>

#define BATCH 2048
#define IN_DIM 784
#define NQ 14
#define NC 10
#define NF 105

// Analytic collapse of the quantum feature map:
//   angles  = tanh(x @ proj_w.T + proj_b) * pi
//   c_q     = cos(angle_q)
//   final bit k of circuit = XOR of initial bits {k, k-2, k-4, ...}
//   <Z_i>    = prod_{q in S_i} c_q;  <Z_i Z_j> = prod over S_i XOR S_j
//   out      = feats @ cls_w.T + cls_b
// zmask(q) = (0x1555 << (q&1)) & ((2u<<q)-1)
//
// R7: R5 structure (1 wave/row, DPP reductions, fast transcendentals) +
// MLP-hoisted pw loads: two batches of 7 q's (28 float4 VMEM in flight per
// batch) instead of per-q load->FMA interleave. ~165 VGPR, keeps 8 waves/CU.

__device__ __forceinline__ unsigned zmask(int q) {
    return (0x1555u << (q & 1)) & ((2u << q) - 1u);
}

template <int CTRL>
__device__ __forceinline__ float dppadd(float x) {
    return x + __int_as_float(__builtin_amdgcn_update_dpp(
        0, __float_as_int(x), CTRL, 0xF, 0xF, true));
}

__device__ __forceinline__ float wave_allreduce(float x, int xor32addr) {
    x = dppadd<0xB1>(x);   // + lane^1
    x = dppadd<0x4E>(x);   // + lane^2
    x = dppadd<0x141>(x);  // + lane^4 (row_half_mirror)
    x = dppadd<0x140>(x);  // + lane^8 (row_mirror)
    x = x + __int_as_float(__builtin_amdgcn_ds_swizzle(__float_as_int(x), 0x401F)); // + lane^16
#if __has_builtin(__builtin_amdgcn_permlane32_swap)
    {
        typedef unsigned u2v __attribute__((ext_vector_type(2)));
        u2v r = __builtin_amdgcn_permlane32_swap(
            (unsigned)__float_as_int(x), (unsigned)__float_as_int(x), false, false);
        x = __int_as_float((int)r[0]) + __int_as_float((int)r[1]);  // x[l&~32]+x[l|32]
    }
#else
    x = x + __int_as_float(__builtin_amdgcn_ds_bpermute(xor32addr, __float_as_int(x)));
#endif
    return x;
}

__device__ __forceinline__ float dot4(const float4 a, const float4 b) {
    return a.x * b.x + a.y * b.y + a.z * b.z + a.w * b.w;
}

__global__ __launch_bounds__(256) void qfm_kernel(
    const float* __restrict__ x,
    const float* __restrict__ pw,
    const float* __restrict__ pb,
    const float* __restrict__ cw,
    const float* __restrict__ cb,
    float* __restrict__ out)
{
    const int wave = (int)((blockIdx.x * blockDim.x + threadIdx.x) >> 6);
    const int lane = (int)(threadIdx.x & 63);
    const int xor32addr = ((lane ^ 32) << 2);

    // ---- load x row: 196 float4 chunks, 3 per lane + remainder ----
    const float4* xr4 = reinterpret_cast<const float4*>(x + (size_t)wave * IN_DIM);
    float4 xv[3];
#pragma unroll
    for (int k = 0; k < 3; ++k) xv[k] = xr4[lane + 64 * k];
    float4 xrem = make_float4(0.f, 0.f, 0.f, 0.f);
    if (lane < 4) xrem = xr4[192 + lane];

    // ---- 14 projection dots, two MLP batches of 7 q's ----
    float acc[NQ];
#pragma unroll
    for (int b = 0; b < 2; ++b) {
        float4 wv[7][3];
        float4 wrem[7];
        // issue all 21 main loads (+7 masked remainder loads) before consuming
#pragma unroll
        for (int u = 0; u < 7; ++u) {
            const float4* wr4 = reinterpret_cast<const float4*>(
                pw + (size_t)(b * 7 + u) * IN_DIM);
#pragma unroll
            for (int k = 0; k < 3; ++k) wv[u][k] = wr4[lane + 64 * k];
        }
        if (lane < 4) {
#pragma unroll
            for (int u = 0; u < 7; ++u)
                wrem[u] = reinterpret_cast<const float4*>(
                    pw + (size_t)(b * 7 + u) * IN_DIM)[192 + lane];
        }
        // consume
#pragma unroll
        for (int u = 0; u < 7; ++u)
            acc[b * 7 + u] = dot4(xv[0], wv[u][0]) + dot4(xv[1], wv[u][1])
                           + dot4(xv[2], wv[u][2]);
        if (lane < 4) {
#pragma unroll
            for (int u = 0; u < 7; ++u)
                acc[b * 7 + u] += dot4(xrem, wrem[u]);
        }
    }

    // ---- wave allreduce per q (VALU DPP butterflies) ----
#pragma unroll
    for (int q = 0; q < NQ; ++q) acc[q] = wave_allreduce(acc[q], xor32addr);

    // ---- fast cos(pi * tanh(a)) ----
    float c[NQ];
#pragma unroll
    for (int q = 0; q < NQ; ++q) {
        const float a = acc[q] + pb[q];
        const float e = __expf(2.0f * a);                 // e^{2a}
        const float r = __builtin_amdgcn_rcpf(e + 1.0f);  // 1/(e^{2a}+1)
        const float t = fmaf(-2.0f, r, 1.0f);             // tanh(a)
        c[q] = __cosf(3.14159265358979323846f * t);       // cos(pi*tanh)
    }

    // ---- features: lane handles f = lane and f = lane + 64 ----
    float acc_out[NC];
#pragma unroll
    for (int k = 0; k < NC; ++k) acc_out[k] = 0.f;

#pragma unroll
    for (int rep = 0; rep < 2; ++rep) {
        const int f = lane + rep * 64;
        if (f < NF) {
            unsigned m;
            if (f < NQ) {
                m = zmask(f);
            } else {
                const int g = f - NQ;                     // 0..90 triangular decode
                const float sq = __builtin_amdgcn_sqrtf(182.25f - 2.0f * (float)g);
                const int i = (int)(13.5f - sq + 1.0e-4f);
                const int j = i + 1 + g - (i * (27 - i)) / 2;
                m = zmask(i) ^ zmask(j);
            }
            float prod = 1.f;
#pragma unroll
            for (int q = 0; q < NQ; ++q) {
                const float mult = ((m >> q) & 1u) ? c[q] : 1.0f;
                prod *= mult;
            }
#pragma unroll
            for (int k = 0; k < NC; ++k)
                acc_out[k] += cw[k * NF + f] * prod;
        }
    }

    // ---- 10 output reductions; lanes 0..9 write coalesced ----
    float myout = 0.f;
#pragma unroll
    for (int k = 0; k < NC; ++k) {
        const float a = wave_allreduce(acc_out[k], xor32addr);
        if (lane == k) myout = a + cb[k];
    }
    if (lane < NC) out[(size_t)wave * NC + lane] = myout;
}

extern "C" void kernel_launch(void* const* d_in, const int* in_sizes, int n_in,
                              void* d_out, int out_size, void* d_ws, size_t ws_size,
                              hipStream_t stream) {
    const float* x  = (const float*)d_in[0];
    const float* pw = (const float*)d_in[1];
    const float* pb = (const float*)d_in[2];
    const float* cw = (const float*)d_in[3];
    const float* cb = (const float*)d_in[4];
    float* out = (float*)d_out;

    qfm_kernel<<<dim3(BATCH / 4), dim3(256), 0, stream>>>(x, pw, pb, cw, cb, out);
}